// Round 1
// baseline (3960.522 us; speedup 1.0000x reference)
//
#include <hip/hip_runtime.h>
#include <math.h>

#define N_NODES 100000

// ---------------- degree computation ----------------
__global__ void deg_kernel(const int* __restrict__ src, const int* __restrict__ dst,
                           int* __restrict__ deg_out, int* __restrict__ deg_in, int E) {
    int i = blockIdx.x * blockDim.x + threadIdx.x;
    if (i < E) {
        atomicAdd(&deg_out[src[i]], 1);
        atomicAdd(&deg_in[dst[i]], 1);
    }
}

__global__ void isqrt_kernel(const int* __restrict__ deg_out, const int* __restrict__ deg_in,
                             float* __restrict__ iso, float* __restrict__ isi, int n) {
    int i = blockIdx.x * blockDim.x + threadIdx.x;
    if (i < n) {
        iso[i] = rsqrtf(fmaxf((float)deg_out[i], 1.0f));
        isi[i] = rsqrtf(fmaxf((float)deg_in[i], 1.0f));
    }
}

// ---------------- dense matmul (x @ W) with src-degree row scaling ----------------
// x: [n,64], W: [64,DOUT], out[row,j] = iso[row] * sum_k x[row,k] * W[k,j]
template <int DOUT>
__global__ void matmul_scale_kernel(const float* __restrict__ x, const float* __restrict__ W,
                                    const float* __restrict__ iso, float* __restrict__ out, int n) {
    __shared__ float Ws[64 * DOUT];
    for (int t = threadIdx.x; t < 64 * DOUT; t += blockDim.x) Ws[t] = W[t];
    __syncthreads();

    const int rpb = 256 / DOUT;              // rows per block
    const int r = threadIdx.x / DOUT;        // local row
    const int j = threadIdx.x % DOUT;        // output column

    for (int row = blockIdx.x * rpb + r; row < n; row += gridDim.x * rpb) {
        float acc = 0.0f;
        if (DOUT == 64) {
            // one row per wave; lane j holds x[row][j], broadcast via shfl
            float xv = x[(long long)row * 64 + j];
#pragma unroll
            for (int k = 0; k < 64; ++k) {
                acc += __shfl(xv, k, 64) * Ws[k * DOUT + j];
            }
        } else {
            // DOUT == 32: two rows per wave, 32-lane groups
            float xv0 = x[(long long)row * 64 + j];
            float xv1 = x[(long long)row * 64 + 32 + j];
#pragma unroll
            for (int k = 0; k < 32; ++k) {
                acc += __shfl(xv0, k, 32) * Ws[k * DOUT + j];
                acc += __shfl(xv1, k, 32) * Ws[(32 + k) * DOUT + j];
            }
        }
        out[(long long)row * DOUT + j] = acc * iso[row];
    }
}

// ---------------- edge aggregation: agg[dst] += h[src] ----------------
// D floats per edge; each thread handles one float4 chunk (D/4 threads per edge).
template <int D>
__global__ void aggregate_kernel(const float* __restrict__ h, const int* __restrict__ src,
                                 const int* __restrict__ dst, float* __restrict__ agg, int total) {
    const int CPE = D / 4;  // float4 chunks per edge
    int tid = blockIdx.x * blockDim.x + threadIdx.x;
    if (tid >= total) return;
    int e = tid / CPE;
    int c = tid % CPE;
    int s = src[e];
    int d = dst[e];
    const float4 v = *reinterpret_cast<const float4*>(&h[(long long)s * D + c * 4]);
    float* a = &agg[(long long)d * D + c * 4];
    atomicAdd(a + 0, v.x);
    atomicAdd(a + 1, v.y);
    atomicAdd(a + 2, v.z);
    atomicAdd(a + 3, v.w);
}

// ---------------- layer epilogue: act(agg * isi + b) ----------------
// ACT: 0 = tanh, 1 = relu
template <int ACT>
__global__ void epilogue_kernel(const float* __restrict__ agg, const float* __restrict__ isi,
                                const float* __restrict__ b, float* __restrict__ out, int total) {
    int i = blockIdx.x * blockDim.x + threadIdx.x;
    if (i >= total) return;
    int row = i >> 6;  // /64
    int col = i & 63;
    float v = agg[i] * isi[row] + b[col];
    if (ACT == 0) v = tanhf(v);
    else v = fmaxf(v, 0.0f);
    out[i] = v;
}

// ---------------- final: z_mean, z_log_std, z_adj ----------------
__global__ void final_kernel(const float* __restrict__ agg, const float* __restrict__ isi,
                             const float* __restrict__ bm, const float* __restrict__ eps,
                             float* __restrict__ out, int total /* N*32 */) {
    int i = blockIdx.x * blockDim.x + threadIdx.x;
    if (i >= total) return;
    int row = i >> 5;  // /32
    int col = i & 31;
    float z = agg[i] * isi[row] + bm[col];
    out[i] = z + expf(z) * eps[i];          // z_adj
    out[total + i] = z;                     // z_log_std
    out[2 * total + i] = z;                 // z_mean
}

static inline size_t align_up(size_t x, size_t a) { return (x + a - 1) & ~(a - 1); }

extern "C" void kernel_launch(void* const* d_in, const int* in_sizes, int n_in,
                              void* d_out, int out_size, void* d_ws, size_t ws_size,
                              hipStream_t stream) {
    const float* feat = (const float*)d_in[0];   // [N,64]
    const int* src = (const int*)d_in[1];        // [E]
    const int* dst = (const int*)d_in[2];        // [E]
    const float* eps = (const float*)d_in[3];    // [N,32]
    const float* W1 = (const float*)d_in[4];     // [64,64]
    const float* b1 = (const float*)d_in[5];     // [64]
    const float* W2 = (const float*)d_in[6];     // [64,64]
    const float* b2 = (const float*)d_in[7];     // [64]
    const float* Wm = (const float*)d_in[8];     // [64,32]
    const float* bm = (const float*)d_in[9];     // [32]

    const int N = N_NODES;
    const int E = in_sizes[1];
    float* out = (float*)d_out;

    // workspace carve-up
    char* ws = (char*)d_ws;
    size_t off = 0;
    int* deg_out = (int*)(ws + off); off = align_up(off + (size_t)N * 4, 256);
    int* deg_in  = (int*)(ws + off); off = align_up(off + (size_t)N * 4, 256);
    float* iso   = (float*)(ws + off); off = align_up(off + (size_t)N * 4, 256);
    float* isi   = (float*)(ws + off); off = align_up(off + (size_t)N * 4, 256);
    float* bufA  = (float*)(ws + off); off = align_up(off + (size_t)N * 64 * 4, 256);  // xw (scaled)
    float* bufB  = (float*)(ws + off); off = align_up(off + (size_t)N * 64 * 4, 256);  // agg
    float* bufC  = (float*)(ws + off); off = align_up(off + (size_t)N * 64 * 4, 256);  // h1 / h2
    (void)ws_size;

    const int B = 256;

    // ---- degrees ----
    hipMemsetAsync(deg_out, 0, (size_t)N * 4, stream);
    hipMemsetAsync(deg_in, 0, (size_t)N * 4, stream);
    deg_kernel<<<(E + B - 1) / B, B, 0, stream>>>(src, dst, deg_out, deg_in, E);
    isqrt_kernel<<<(N + B - 1) / B, B, 0, stream>>>(deg_out, deg_in, iso, isi, N);

    // ---- layer 1: h1 = tanh(conv(feat, W1, b1)) ----
    matmul_scale_kernel<64><<<(N + 3) / 4, B, 0, stream>>>(feat, W1, iso, bufA, N);
    hipMemsetAsync(bufB, 0, (size_t)N * 64 * 4, stream);
    {
        int total = E * 16;
        aggregate_kernel<64><<<(total + B - 1) / B, B, 0, stream>>>(bufA, src, dst, bufB, total);
    }
    epilogue_kernel<0><<<(N * 64 + B - 1) / B, B, 0, stream>>>(bufB, isi, b1, bufC, N * 64);

    // ---- layer 2: h2 = relu(conv(h1, W2, b2)) ----
    matmul_scale_kernel<64><<<(N + 3) / 4, B, 0, stream>>>(bufC, W2, iso, bufA, N);
    hipMemsetAsync(bufB, 0, (size_t)N * 64 * 4, stream);
    {
        int total = E * 16;
        aggregate_kernel<64><<<(total + B - 1) / B, B, 0, stream>>>(bufA, src, dst, bufB, total);
    }
    epilogue_kernel<1><<<(N * 64 + B - 1) / B, B, 0, stream>>>(bufB, isi, b2, bufC, N * 64);

    // ---- layer 3: z = conv(h2, Wm, bm); applied Wm BEFORE aggregation (linearity) ----
    matmul_scale_kernel<32><<<(N + 7) / 8, B, 0, stream>>>(bufC, Wm, iso, bufA, N);
    hipMemsetAsync(bufB, 0, (size_t)N * 32 * 4, stream);
    {
        int total = E * 8;
        aggregate_kernel<32><<<(total + B - 1) / B, B, 0, stream>>>(bufA, src, dst, bufB, total);
    }
    final_kernel<<<(N * 32 + B - 1) / B, B, 0, stream>>>(bufB, isi, bm, eps, out, N * 32);
}

// Round 3
// 872.672 us; speedup vs baseline: 4.5384x; 4.5384x over previous
//
#include <hip/hip_runtime.h>
#include <math.h>

#define N_NODES 100000

// ---------------- degree computation ----------------
__global__ void deg_kernel(const int* __restrict__ src, const int* __restrict__ dst,
                           int* __restrict__ deg_out, int* __restrict__ deg_in, int E) {
    int i = blockIdx.x * blockDim.x + threadIdx.x;
    if (i < E) {
        atomicAdd(&deg_out[src[i]], 1);
        atomicAdd(&deg_in[dst[i]], 1);
    }
}

__global__ void isqrt_kernel(const int* __restrict__ deg_out, const int* __restrict__ deg_in,
                             float* __restrict__ iso, float* __restrict__ isi, int n) {
    int i = blockIdx.x * blockDim.x + threadIdx.x;
    if (i < n) {
        iso[i] = rsqrtf(fmaxf((float)deg_out[i], 1.0f));
        isi[i] = rsqrtf(fmaxf((float)deg_in[i], 1.0f));
    }
}

// ---------------- exclusive prefix scan of deg_in -> row_start ----------------
#define SCAN_BLOCK 256
#define SCAN_ITEMS 8
#define SCAN_CHUNK (SCAN_BLOCK * SCAN_ITEMS)  // 2048

__global__ void scan1_kernel(const int* __restrict__ deg, int* __restrict__ partial,
                             int* __restrict__ block_sums, int n) {
    __shared__ int lds[SCAN_BLOCK];
    int t = threadIdx.x;
    int base = blockIdx.x * SCAN_CHUNK + t * SCAN_ITEMS;
    int vals[SCAN_ITEMS];
    int sum = 0;
#pragma unroll
    for (int k = 0; k < SCAN_ITEMS; ++k) {
        int idx = base + k;
        int v = (idx < n) ? deg[idx] : 0;
        vals[k] = sum;  // exclusive within thread
        sum += v;
    }
    lds[t] = sum;
    __syncthreads();
    // inclusive Hillis-Steele over thread sums
    for (int off = 1; off < SCAN_BLOCK; off <<= 1) {
        int y = (t >= off) ? lds[t - off] : 0;
        __syncthreads();
        lds[t] += y;
        __syncthreads();
    }
    int thread_prefix = lds[t] - sum;  // exclusive prefix of this thread
    if (t == SCAN_BLOCK - 1) block_sums[blockIdx.x] = lds[SCAN_BLOCK - 1];
#pragma unroll
    for (int k = 0; k < SCAN_ITEMS; ++k) {
        int idx = base + k;
        if (idx < n) partial[idx] = thread_prefix + vals[k];
    }
}

__global__ void scan2_kernel(int* __restrict__ block_sums, int nb) {
    if (threadIdx.x == 0 && blockIdx.x == 0) {
        int acc = 0;
        for (int i = 0; i < nb; ++i) {
            int v = block_sums[i];
            block_sums[i] = acc;
            acc += v;
        }
    }
}

__global__ void scan3_kernel(const int* __restrict__ partial, const int* __restrict__ block_sums,
                             int* __restrict__ row_start, int* __restrict__ cursor, int n, int E) {
    int i = blockIdx.x * blockDim.x + threadIdx.x;
    if (i < n) {
        int v = partial[i] + block_sums[i / SCAN_CHUNK];
        row_start[i] = v;
        cursor[i] = v;
    }
    if (i == 0) row_start[n] = E;
}

// ---------------- CSR scatter: group src indices by dst ----------------
__global__ void scatter_kernel(const int* __restrict__ src, const int* __restrict__ dst,
                               int* __restrict__ cursor, int* __restrict__ csr_src, int E) {
    int e = blockIdx.x * blockDim.x + threadIdx.x;
    if (e < E) {
        int pos = atomicAdd(&cursor[dst[e]], 1);
        csr_src[pos] = src[e];
    }
}

// ---------------- dense matmul (x @ W) with src-degree row scaling ----------------
template <int DOUT>
__global__ void matmul_scale_kernel(const float* __restrict__ x, const float* __restrict__ W,
                                    const float* __restrict__ iso, float* __restrict__ out, int n) {
    __shared__ float Ws[64 * DOUT];
    for (int t = threadIdx.x; t < 64 * DOUT; t += blockDim.x) Ws[t] = W[t];
    __syncthreads();

    const int rpb = 256 / DOUT;              // rows per block
    const int r = threadIdx.x / DOUT;        // local row
    const int j = threadIdx.x % DOUT;        // output column

    for (int row = blockIdx.x * rpb + r; row < n; row += gridDim.x * rpb) {
        float acc = 0.0f;
        if (DOUT == 64) {
            float xv = x[(long long)row * 64 + j];
#pragma unroll
            for (int k = 0; k < 64; ++k) {
                acc += __shfl(xv, k, 64) * Ws[k * DOUT + j];
            }
        } else {
            float xv0 = x[(long long)row * 64 + j];
            float xv1 = x[(long long)row * 64 + 32 + j];
#pragma unroll
            for (int k = 0; k < 32; ++k) {
                acc += __shfl(xv0, k, 32) * Ws[k * DOUT + j];
                acc += __shfl(xv1, k, 32) * Ws[(32 + k) * DOUT + j];
            }
        }
        out[(long long)row * DOUT + j] = acc * iso[row];
    }
}

// ---------------- fused gather-aggregate + epilogue ----------------
// One D-lane group per node; lane j owns column j. Per edge: coalesced D*4B row read.
// MODE: 0 = tanh, 1 = relu, 2 = final reparameterization (D must be 32)
template <int D, int MODE>
__global__ void gather_kernel(const float* __restrict__ h, const int* __restrict__ csr_src,
                              const int* __restrict__ row_start, const float* __restrict__ isi,
                              const float* __restrict__ b, const float* __restrict__ eps,
                              float* __restrict__ out, int n) {
    const int GP = 256 / D;  // node groups per block
    int g = threadIdx.x / D;
    int j = threadIdx.x % D;
    int node = blockIdx.x * GP + g;
    if (node >= n) return;

    int beg = row_start[node];
    int end = row_start[node + 1];
    float acc = 0.0f;
    int e = beg;
    for (; e + 4 <= end; e += 4) {
        int s0 = csr_src[e + 0];
        int s1 = csr_src[e + 1];
        int s2 = csr_src[e + 2];
        int s3 = csr_src[e + 3];
        float v0 = h[(long long)s0 * D + j];
        float v1 = h[(long long)s1 * D + j];
        float v2 = h[(long long)s2 * D + j];
        float v3 = h[(long long)s3 * D + j];
        acc += v0 + v1 + v2 + v3;
    }
    for (; e < end; ++e) acc += h[(long long)csr_src[e] * D + j];

    float v = acc * isi[node] + b[j];
    if (MODE == 0) {
        v = tanhf(v);
        out[(long long)node * D + j] = v;
    } else if (MODE == 1) {
        v = fmaxf(v, 0.0f);
        out[(long long)node * D + j] = v;
    } else {
        const int total = N_NODES * 32;
        int i = node * 32 + j;
        out[i] = v + expf(v) * eps[i];  // z_adj
        out[total + i] = v;             // z_log_std
        out[2 * total + i] = v;         // z_mean
    }
}

static inline size_t align_up(size_t x, size_t a) { return (x + a - 1) & ~(a - 1); }

extern "C" void kernel_launch(void* const* d_in, const int* in_sizes, int n_in,
                              void* d_out, int out_size, void* d_ws, size_t ws_size,
                              hipStream_t stream) {
    const float* feat = (const float*)d_in[0];   // [N,64]
    const int* src = (const int*)d_in[1];        // [E]
    const int* dst = (const int*)d_in[2];        // [E]
    const float* eps = (const float*)d_in[3];    // [N,32]
    const float* W1 = (const float*)d_in[4];     // [64,64]
    const float* b1 = (const float*)d_in[5];     // [64]
    const float* W2 = (const float*)d_in[6];     // [64,64]
    const float* b2 = (const float*)d_in[7];     // [64]
    const float* Wm = (const float*)d_in[8];     // [64,32]
    const float* bm = (const float*)d_in[9];     // [32]

    const int N = N_NODES;
    const int E = in_sizes[1];
    float* out = (float*)d_out;

    // workspace carve-up
    char* ws = (char*)d_ws;
    size_t off = 0;
    int* deg_out   = (int*)(ws + off); off = align_up(off + (size_t)N * 4, 256);
    int* deg_in    = (int*)(ws + off); off = align_up(off + (size_t)N * 4, 256);
    float* iso     = (float*)(ws + off); off = align_up(off + (size_t)N * 4, 256);
    float* isi     = (float*)(ws + off); off = align_up(off + (size_t)N * 4, 256);
    int* row_start = (int*)(ws + off); off = align_up(off + (size_t)(N + 1) * 4, 256);
    int* cursor    = (int*)(ws + off); off = align_up(off + (size_t)N * 4, 256);
    int* partial   = (int*)(ws + off); off = align_up(off + (size_t)N * 4, 256);
    int* block_sums= (int*)(ws + off); off = align_up(off + (size_t)64 * 4, 256);
    int* csr_src   = (int*)(ws + off); off = align_up(off + (size_t)E * 4, 256);
    float* bufA    = (float*)(ws + off); off = align_up(off + (size_t)N * 64 * 4, 256);  // x@W (iso-scaled)
    float* bufH    = (float*)(ws + off); off = align_up(off + (size_t)N * 64 * 4, 256);  // h1 / h2
    (void)ws_size;

    const int B = 256;
    const int scan_blocks = (N + SCAN_CHUNK - 1) / SCAN_CHUNK;  // 49

    // ---- degrees ----
    hipMemsetAsync(deg_out, 0, (size_t)N * 4, stream);
    hipMemsetAsync(deg_in, 0, (size_t)N * 4, stream);
    deg_kernel<<<(E + B - 1) / B, B, 0, stream>>>(src, dst, deg_out, deg_in, E);
    isqrt_kernel<<<(N + B - 1) / B, B, 0, stream>>>(deg_out, deg_in, iso, isi, N);

    // ---- CSR build (grouped by dst) ----
    scan1_kernel<<<scan_blocks, SCAN_BLOCK, 0, stream>>>(deg_in, partial, block_sums, N);
    scan2_kernel<<<1, 64, 0, stream>>>(block_sums, scan_blocks);
    scan3_kernel<<<(N + B - 1) / B, B, 0, stream>>>(partial, block_sums, row_start, cursor, N, E);
    scatter_kernel<<<(E + B - 1) / B, B, 0, stream>>>(src, dst, cursor, csr_src, E);

    // ---- layer 1: h1 = tanh(conv(feat, W1, b1)) ----
    matmul_scale_kernel<64><<<(N + 3) / 4, B, 0, stream>>>(feat, W1, iso, bufA, N);
    gather_kernel<64, 0><<<(N + 3) / 4, B, 0, stream>>>(bufA, csr_src, row_start, isi, b1, nullptr, bufH, N);

    // ---- layer 2: h2 = relu(conv(h1, W2, b2)) ----
    matmul_scale_kernel<64><<<(N + 3) / 4, B, 0, stream>>>(bufH, W2, iso, bufA, N);
    gather_kernel<64, 1><<<(N + 3) / 4, B, 0, stream>>>(bufA, csr_src, row_start, isi, b2, nullptr, bufH, N);

    // ---- layer 3: z = conv(h2, Wm, bm); Wm applied BEFORE aggregation (linearity) ----
    matmul_scale_kernel<32><<<(N + 7) / 8, B, 0, stream>>>(bufH, Wm, iso, bufA, N);
    gather_kernel<32, 2><<<(N + 7) / 8, B, 0, stream>>>(bufA, csr_src, row_start, isi, bm, eps, out, N);
}

// Round 4
// 590.524 us; speedup vs baseline: 6.7068x; 1.4778x over previous
//
#include <hip/hip_runtime.h>
#include <math.h>

#define N_NODES 100000

// ---------------- degree computation ----------------
__global__ void deg_kernel(const int* __restrict__ src, const int* __restrict__ dst,
                           int* __restrict__ deg_out, int* __restrict__ deg_in, int E) {
    int i = blockIdx.x * blockDim.x + threadIdx.x;
    if (i < E) {
        atomicAdd(&deg_out[src[i]], 1);
        atomicAdd(&deg_in[dst[i]], 1);
    }
}

__global__ void isqrt_kernel(const int* __restrict__ deg_out, const int* __restrict__ deg_in,
                             float* __restrict__ iso, float* __restrict__ isi, int n) {
    int i = blockIdx.x * blockDim.x + threadIdx.x;
    if (i < n) {
        iso[i] = rsqrtf(fmaxf((float)deg_out[i], 1.0f));
        isi[i] = rsqrtf(fmaxf((float)deg_in[i], 1.0f));
    }
}

// ---------------- exclusive prefix scan of deg_in -> row_start ----------------
#define SCAN_BLOCK 256
#define SCAN_ITEMS 8
#define SCAN_CHUNK (SCAN_BLOCK * SCAN_ITEMS)  // 2048

__global__ void scan1_kernel(const int* __restrict__ deg, int* __restrict__ partial,
                             int* __restrict__ block_sums, int n) {
    __shared__ int lds[SCAN_BLOCK];
    int t = threadIdx.x;
    int base = blockIdx.x * SCAN_CHUNK + t * SCAN_ITEMS;
    int vals[SCAN_ITEMS];
    int sum = 0;
#pragma unroll
    for (int k = 0; k < SCAN_ITEMS; ++k) {
        int idx = base + k;
        int v = (idx < n) ? deg[idx] : 0;
        vals[k] = sum;  // exclusive within thread
        sum += v;
    }
    lds[t] = sum;
    __syncthreads();
    for (int off = 1; off < SCAN_BLOCK; off <<= 1) {
        int y = (t >= off) ? lds[t - off] : 0;
        __syncthreads();
        lds[t] += y;
        __syncthreads();
    }
    int thread_prefix = lds[t] - sum;
    if (t == SCAN_BLOCK - 1) block_sums[blockIdx.x] = lds[SCAN_BLOCK - 1];
#pragma unroll
    for (int k = 0; k < SCAN_ITEMS; ++k) {
        int idx = base + k;
        if (idx < n) partial[idx] = thread_prefix + vals[k];
    }
}

__global__ void scan2_kernel(int* __restrict__ block_sums, int nb) {
    if (threadIdx.x == 0 && blockIdx.x == 0) {
        int acc = 0;
        for (int i = 0; i < nb; ++i) {
            int v = block_sums[i];
            block_sums[i] = acc;
            acc += v;
        }
    }
}

__global__ void scan3_kernel(const int* __restrict__ partial, const int* __restrict__ block_sums,
                             int* __restrict__ row_start, int* __restrict__ cursor, int n, int E) {
    int i = blockIdx.x * blockDim.x + threadIdx.x;
    if (i < n) {
        int v = partial[i] + block_sums[i / SCAN_CHUNK];
        row_start[i] = v;
        cursor[i] = v;
    }
    if (i == 0) row_start[n] = E;
}

// ---------------- CSR scatter: group src indices by dst ----------------
__global__ void scatter_kernel(const int* __restrict__ src, const int* __restrict__ dst,
                               int* __restrict__ cursor, int* __restrict__ csr_src, int E) {
    int e = blockIdx.x * blockDim.x + threadIdx.x;
    if (e < E) {
        int pos = atomicAdd(&cursor[dst[e]], 1);
        csr_src[pos] = src[e];
    }
}

// ---------------- register-blocked GEMM: out = diag(iso) * (x @ W) ----------------
// x: [n,64], W: [64,DOUT]. LDS: W tile + transposed-swizzled x tile.
// Each thread computes a 4x4 micro-tile; per k: 2x ds_read_b128 + 16 FMA.
template <int DOUT>
__global__ __launch_bounds__(256) void gemm_scale_kernel(const float* __restrict__ x,
                                                         const float* __restrict__ W,
                                                         const float* __restrict__ iso,
                                                         float* __restrict__ out, int n) {
    constexpr int TC = DOUT / 4;   // col-threads: 16 (DOUT=64) or 8 (DOUT=32)
    constexpr int TR = 256 / TC;   // row-threads: 16 or 32
    constexpr int ROWS = TR * 4;   // rows per block: 64 or 128

    __shared__ float Xs[64 * ROWS];   // [k][row ^ swz(k)]
    __shared__ float Ws[64 * DOUT];   // [k][j]

    const int t = threadIdx.x;
    const int row_base = blockIdx.x * ROWS;

    // stage W (coalesced float4)
    {
        const float4* Wg = reinterpret_cast<const float4*>(W);
        float4* Ws4 = reinterpret_cast<float4*>(Ws);
        for (int i = t; i < 64 * TC; i += 256) Ws4[i] = Wg[i];
    }
    // stage x tile: load row-major float4, store transposed with XOR swizzle.
    // element (k=kq*4+c, r) -> Xs[k*ROWS + (r ^ ((kq&7)<<2))]
    {
        const float4* xg = reinterpret_cast<const float4*>(x);
#pragma unroll
        for (int it = 0; it < ROWS / 16; ++it) {
            int f = t + it * 256;
            int r = f >> 4;        // local row 0..ROWS-1
            int kq = f & 15;       // k-quad 0..15
            int row = row_base + r;
            int rcl = row < n ? row : n - 1;
            float4 v = xg[(size_t)rcl * 16 + kq];
            int rp = r ^ ((kq & 7) << 2);
            Xs[(kq * 4 + 0) * ROWS + rp] = v.x;
            Xs[(kq * 4 + 1) * ROWS + rp] = v.y;
            Xs[(kq * 4 + 2) * ROWS + rp] = v.z;
            Xs[(kq * 4 + 3) * ROWS + rp] = v.w;
        }
    }
    __syncthreads();

    const int tc = t % TC;  // col group: cols tc*4..+3
    const int tr = t / TC;  // row group: rows tr*4..+3

    float acc[4][4];
#pragma unroll
    for (int i = 0; i < 4; ++i)
#pragma unroll
        for (int j = 0; j < 4; ++j) acc[i][j] = 0.0f;

    const float4* Xs4 = reinterpret_cast<const float4*>(Xs);
    const float4* Ws4 = reinterpret_cast<const float4*>(Ws);

#pragma unroll 8
    for (int k = 0; k < 64; ++k) {
        float4 a = Xs4[k * (ROWS / 4) + (tr ^ ((k >> 2) & 7))];
        float4 b = Ws4[k * TC + tc];
        acc[0][0] += a.x * b.x; acc[0][1] += a.x * b.y; acc[0][2] += a.x * b.z; acc[0][3] += a.x * b.w;
        acc[1][0] += a.y * b.x; acc[1][1] += a.y * b.y; acc[1][2] += a.y * b.z; acc[1][3] += a.y * b.w;
        acc[2][0] += a.z * b.x; acc[2][1] += a.z * b.y; acc[2][2] += a.z * b.z; acc[2][3] += a.z * b.w;
        acc[3][0] += a.w * b.x; acc[3][1] += a.w * b.y; acc[3][2] += a.w * b.z; acc[3][3] += a.w * b.w;
    }

#pragma unroll
    for (int i = 0; i < 4; ++i) {
        int row = row_base + tr * 4 + i;
        if (row < n) {
            float sc = iso[row];
            float4 o;
            o.x = acc[i][0] * sc;
            o.y = acc[i][1] * sc;
            o.z = acc[i][2] * sc;
            o.w = acc[i][3] * sc;
            reinterpret_cast<float4*>(out)[(size_t)row * TC + tc] = o;
        }
    }
}

// ---------------- fused gather-aggregate + epilogue ----------------
// One D-lane group per node; lane j owns column j. Per edge: coalesced D*4B row read.
// MODE: 0 = tanh, 1 = relu, 2 = final reparameterization (D must be 32)
template <int D, int MODE>
__global__ void gather_kernel(const float* __restrict__ h, const int* __restrict__ csr_src,
                              const int* __restrict__ row_start, const float* __restrict__ isi,
                              const float* __restrict__ b, const float* __restrict__ eps,
                              float* __restrict__ out, int n) {
    const int GP = 256 / D;  // node groups per block
    int g = threadIdx.x / D;
    int j = threadIdx.x % D;
    int node = blockIdx.x * GP + g;
    if (node >= n) return;

    int beg = row_start[node];
    int end = row_start[node + 1];
    float acc = 0.0f;
    int e = beg;
    for (; e + 4 <= end; e += 4) {
        int s0 = csr_src[e + 0];
        int s1 = csr_src[e + 1];
        int s2 = csr_src[e + 2];
        int s3 = csr_src[e + 3];
        float v0 = h[(long long)s0 * D + j];
        float v1 = h[(long long)s1 * D + j];
        float v2 = h[(long long)s2 * D + j];
        float v3 = h[(long long)s3 * D + j];
        acc += v0 + v1 + v2 + v3;
    }
    for (; e < end; ++e) acc += h[(long long)csr_src[e] * D + j];

    float v = acc * isi[node] + b[j];
    if (MODE == 0) {
        v = tanhf(v);
        out[(long long)node * D + j] = v;
    } else if (MODE == 1) {
        v = fmaxf(v, 0.0f);
        out[(long long)node * D + j] = v;
    } else {
        const int total = N_NODES * 32;
        int i = node * 32 + j;
        out[i] = v + expf(v) * eps[i];  // z_adj
        out[total + i] = v;             // z_log_std
        out[2 * total + i] = v;         // z_mean
    }
}

static inline size_t align_up(size_t x, size_t a) { return (x + a - 1) & ~(a - 1); }

extern "C" void kernel_launch(void* const* d_in, const int* in_sizes, int n_in,
                              void* d_out, int out_size, void* d_ws, size_t ws_size,
                              hipStream_t stream) {
    const float* feat = (const float*)d_in[0];   // [N,64]
    const int* src = (const int*)d_in[1];        // [E]
    const int* dst = (const int*)d_in[2];        // [E]
    const float* eps = (const float*)d_in[3];    // [N,32]
    const float* W1 = (const float*)d_in[4];     // [64,64]
    const float* b1 = (const float*)d_in[5];     // [64]
    const float* W2 = (const float*)d_in[6];     // [64,64]
    const float* b2 = (const float*)d_in[7];     // [64]
    const float* Wm = (const float*)d_in[8];     // [64,32]
    const float* bm = (const float*)d_in[9];     // [32]

    const int N = N_NODES;
    const int E = in_sizes[1];
    float* out = (float*)d_out;

    // workspace carve-up
    char* ws = (char*)d_ws;
    size_t off = 0;
    int* deg_out   = (int*)(ws + off); off = align_up(off + (size_t)N * 4, 256);
    int* deg_in    = (int*)(ws + off); off = align_up(off + (size_t)N * 4, 256);
    float* iso     = (float*)(ws + off); off = align_up(off + (size_t)N * 4, 256);
    float* isi     = (float*)(ws + off); off = align_up(off + (size_t)N * 4, 256);
    int* row_start = (int*)(ws + off); off = align_up(off + (size_t)(N + 1) * 4, 256);
    int* cursor    = (int*)(ws + off); off = align_up(off + (size_t)N * 4, 256);
    int* partial   = (int*)(ws + off); off = align_up(off + (size_t)N * 4, 256);
    int* block_sums= (int*)(ws + off); off = align_up(off + (size_t)64 * 4, 256);
    int* csr_src   = (int*)(ws + off); off = align_up(off + (size_t)E * 4, 256);
    float* bufA    = (float*)(ws + off); off = align_up(off + (size_t)N * 64 * 4, 256);  // x@W (iso-scaled)
    float* bufH    = (float*)(ws + off); off = align_up(off + (size_t)N * 64 * 4, 256);  // h1 / h2
    (void)ws_size;

    const int B = 256;
    const int scan_blocks = (N + SCAN_CHUNK - 1) / SCAN_CHUNK;  // 49

    // ---- degrees ----
    hipMemsetAsync(deg_out, 0, (size_t)N * 4, stream);
    hipMemsetAsync(deg_in, 0, (size_t)N * 4, stream);
    deg_kernel<<<(E + B - 1) / B, B, 0, stream>>>(src, dst, deg_out, deg_in, E);
    isqrt_kernel<<<(N + B - 1) / B, B, 0, stream>>>(deg_out, deg_in, iso, isi, N);

    // ---- CSR build (grouped by dst) ----
    scan1_kernel<<<scan_blocks, SCAN_BLOCK, 0, stream>>>(deg_in, partial, block_sums, N);
    scan2_kernel<<<1, 64, 0, stream>>>(block_sums, scan_blocks);
    scan3_kernel<<<(N + B - 1) / B, B, 0, stream>>>(partial, block_sums, row_start, cursor, N, E);
    scatter_kernel<<<(E + B - 1) / B, B, 0, stream>>>(src, dst, cursor, csr_src, E);

    // ---- layer 1: h1 = tanh(conv(feat, W1, b1)) ----
    gemm_scale_kernel<64><<<(N + 63) / 64, B, 0, stream>>>(feat, W1, iso, bufA, N);
    gather_kernel<64, 0><<<(N + 3) / 4, B, 0, stream>>>(bufA, csr_src, row_start, isi, b1, nullptr, bufH, N);

    // ---- layer 2: h2 = relu(conv(h1, W2, b2)) ----
    gemm_scale_kernel<64><<<(N + 63) / 64, B, 0, stream>>>(bufH, W2, iso, bufA, N);
    gather_kernel<64, 1><<<(N + 3) / 4, B, 0, stream>>>(bufA, csr_src, row_start, isi, b2, nullptr, bufH, N);

    // ---- layer 3: z = conv(h2, Wm, bm); Wm applied BEFORE aggregation (linearity) ----
    gemm_scale_kernel<32><<<(N + 127) / 128, B, 0, stream>>>(bufH, Wm, iso, bufA, N);
    gather_kernel<32, 2><<<(N + 7) / 8, B, 0, stream>>>(bufA, csr_src, row_start, isi, bm, eps, out, N);
}